// Round 7
// baseline (323.810 us; speedup 1.0000x reference)
//
#include <hip/hip_runtime.h>
#include <hip/hip_bf16.h>
#include <math.h>

#define BB 16
#define SS 2048
#define DD 512
#define MM 256
#define RR 64
#define KK 16

__device__ __forceinline__ float wave_sum(float v) {
#pragma unroll
  for (int off = 32; off > 0; off >>= 1) v += __shfl_xor(v, off);
  return v;
}

__device__ __forceinline__ float sgnf(float v) {
  return (v > 0.f) ? 1.f : ((v < 0.f) ? -1.f : 0.f);
}

// ---------------------------------------------------------------------------
// LN(init_val) -> mv0 [M,D]; pt0[m,r] = (mv0[m]·rUt_w[:,r] + rUt_b[r])*r_w[r]*0.1
// ---------------------------------------------------------------------------
__global__ __launch_bounds__(256) void k_init(
    const float* __restrict__ init_val, const float* __restrict__ ln_g,
    const float* __restrict__ ln_b, const float* __restrict__ rUt_w,
    const float* __restrict__ rUt_b, const float* __restrict__ r_w,
    float* __restrict__ mv0, float* __restrict__ pt0) {
  int m = blockIdx.x, t = threadIdx.x;
  __shared__ float row[DD];
  __shared__ float red[8];
  float x0 = init_val[m * DD + t];
  float x1 = init_val[m * DD + t + 256];
  float s = wave_sum(x0 + x1);
  float sq = wave_sum(x0 * x0 + x1 * x1);
  if ((t & 63) == 0) { red[t >> 6] = s; red[4 + (t >> 6)] = sq; }
  __syncthreads();
  float mean = (red[0] + red[1] + red[2] + red[3]) * (1.0f / DD);
  float var = (red[4] + red[5] + red[6] + red[7]) * (1.0f / DD) - mean * mean;
  float rs = rsqrtf(var + 1e-5f);
  float n0 = (x0 - mean) * rs * ln_g[t] + ln_b[t];
  float n1 = (x1 - mean) * rs * ln_g[t + 256] + ln_b[t + 256];
  mv0[m * DD + t] = n0;
  mv0[m * DD + t + 256] = n1;
  row[t] = n0;
  row[t + 256] = n1;
  __syncthreads();
  if (t < RR) {
    float acc = rUt_b[t];
    for (int d = 0; d < DD; ++d) acc += row[d] * rUt_w[d * RR + t];
    pt0[m * RR + t] = acc * r_w[t] * 0.1f;
  }
}

// ---------------------------------------------------------------------------
// signed_softmax_state over 256 elements per block-row
// ---------------------------------------------------------------------------
__global__ __launch_bounds__(256) void k_state_softmax(
    const float* __restrict__ in, float* __restrict__ out) {
  int b = blockIdx.x, t = threadIdx.x;
  __shared__ float red[4];
  float v = in[b * MM + t];
  float a = fabsf(v);
  float mx = a;
#pragma unroll
  for (int off = 32; off > 0; off >>= 1) mx = fmaxf(mx, __shfl_xor(mx, off));
  if ((t & 63) == 0) red[t >> 6] = mx;
  __syncthreads();
  mx = fmaxf(fmaxf(red[0], red[1]), fmaxf(red[2], red[3]));
  __syncthreads();
  float e = expf(a - mx);
  float ssum = wave_sum(e);
  if ((t & 63) == 0) red[t >> 6] = ssum;
  __syncthreads();
  ssum = red[0] + red[1] + red[2] + red[3];
  out[b * MM + t] = sgnf(v) * e / ssum * 4.0f;
}

// ---------------------------------------------------------------------------
// SGPR-A skinny GEMM: lane = output column (64 cols = 1 wave), wave = ROWS
// rows. W staged in LDS (linear copy, conflict-free); per k one ds_read_b32
// (bank=lane, free). A rows read via wave-uniform addresses -> scalar loads
// (separate pipe). VALU-bound by design.
// ---------------------------------------------------------------------------
template <int ROWS, bool TRANS_OUT>
__device__ __forceinline__ void gemm_sg_body(
    const float* __restrict__ A, const float* __restrict__ W,
    const float* __restrict__ bias, const float* __restrict__ colscale,
    float csmul, const float* __restrict__ rowscale, float* __restrict__ C,
    int row0, float (*Ws)[RR]) {
  int t = threadIdx.x;
  int lane = t & 63;
  float acc[ROWS] = {};
  for (int kc = 0; kc < DD; kc += 128) {
    __syncthreads();
    // stage W chunk [128][64] as a linear float4 copy (no conflicts)
#pragma unroll
    for (int i = 0; i < 8; ++i) {
      int g = i * 1024 + t * 4;
      *reinterpret_cast<float4*>(&Ws[0][0] + g) =
          *reinterpret_cast<const float4*>(W + (size_t)kc * RR + g);
    }
    __syncthreads();
#pragma unroll 4
    for (int k4 = 0; k4 < 32; ++k4) {
      float4 sa[ROWS];
#pragma unroll
      for (int r = 0; r < ROWS; ++r)
        sa[r] = *reinterpret_cast<const float4*>(
            A + (size_t)(row0 + r) * DD + kc + k4 * 4);
      float w0 = Ws[k4 * 4 + 0][lane];
      float w1 = Ws[k4 * 4 + 1][lane];
      float w2 = Ws[k4 * 4 + 2][lane];
      float w3 = Ws[k4 * 4 + 3][lane];
#pragma unroll
      for (int r = 0; r < ROWS; ++r) {
        acc[r] += sa[r].x * w0;
        acc[r] += sa[r].y * w1;
        acc[r] += sa[r].z * w2;
        acc[r] += sa[r].w * w3;
      }
    }
  }
  float cs = colscale ? colscale[lane] * csmul : 1.f;
  float bv = bias[lane];
#pragma unroll
  for (int r = 0; r < ROWS; ++r) {
    int rr = row0 + r;
    float v = acc[r] + bv;
    if (colscale) v *= cs;
    if (rowscale) v *= rowscale[rr];
    if (TRANS_OUT) {
      C[((size_t)(rr >> 8) * RR + lane) * MM + (rr & 255)] = v;
    } else {
      C[(size_t)rr * RR + lane] = v;
    }
  }
}

// ps = token_val @ rUs_w + b : 32768 rows, 16 rows/wave, 512 blocks.
__global__ __launch_bounds__(256) void k_ps(
    const float* __restrict__ A, const float* __restrict__ W,
    const float* __restrict__ bias, float* __restrict__ C) {
  __shared__ float Ws[128][RR];
  int wv = __builtin_amdgcn_readfirstlane(threadIdx.x >> 6);
  int row0 = blockIdx.x * 64 + wv * 16;
  gemm_sg_body<16, false>(A, W, bias, nullptr, 1.f, nullptr, C, row0, Ws);
}

// pt1 (cols scaled p_w*0.1) and ps1T (rows scaled ms1, transposed) fused:
// 4096 rows each, 8 rows/wave, 128+128 blocks.
__global__ __launch_bounds__(256) void k_gemm_pair(
    const float* __restrict__ mv1, const float* __restrict__ pUt_w,
    const float* __restrict__ pUt_b, const float* __restrict__ p_w,
    const float* __restrict__ pUs_w, const float* __restrict__ pUs_b,
    const float* __restrict__ ms1, float* __restrict__ pt1,
    float* __restrict__ ps1T) {
  __shared__ float Ws[128][RR];
  int wv = __builtin_amdgcn_readfirstlane(threadIdx.x >> 6);
  if (blockIdx.x < 128) {
    int row0 = blockIdx.x * 32 + wv * 8;
    gemm_sg_body<8, false>(mv1, pUt_w, pUt_b, p_w, 0.1f, nullptr, pt1, row0,
                           Ws);
  } else {
    int row0 = (blockIdx.x - 128) * 32 + wv * 8;
    gemm_sg_body<8, true>(mv1, pUs_w, pUs_b, nullptr, 1.f, ms1, ps1T, row0,
                          Ws);
  }
}

// ---------------------------------------------------------------------------
// scores[b,m,j] = pt0[m,:]·ps[b,j,:]  (K=64). Wave owns a 64-j chunk: ps row
// held in 64 VGPRs (loaded once), pt0 rows streamed via uniform scalar loads.
// Each wave computes 64 m rows. grid (32 jc, 16 b), 4 waves/block.
// ---------------------------------------------------------------------------
__global__ __launch_bounds__(256) void k_scores(
    const float* __restrict__ pt0, const float* __restrict__ ps,
    float* __restrict__ scores) {
  int t = threadIdx.x;
  int lane = t & 63;
  int wv = __builtin_amdgcn_readfirstlane(t >> 6);
  int b = blockIdx.y;
  int j = blockIdx.x * 64 + lane;
  float4 pr[16];
  const float* psrow = ps + ((size_t)b * SS + j) * RR;
#pragma unroll
  for (int r4 = 0; r4 < 16; ++r4)
    pr[r4] = *reinterpret_cast<const float4*>(psrow + r4 * 4);
  int mbase = wv * 64;
  float* obase = scores + (size_t)b * MM * SS + (size_t)mbase * SS + j;
  for (int mi = 0; mi < 64; ++mi) {
    const float* ptrow = pt0 + (mbase + mi) * RR;
    float acc = 0.f;
#pragma unroll
    for (int r4 = 0; r4 < 16; ++r4) {
      float4 p = *reinterpret_cast<const float4*>(ptrow + r4 * 4);
      acc += p.x * pr[r4].x + p.y * pr[r4].y + p.z * pr[r4].z + p.w * pr[r4].w;
    }
    obase[(size_t)mi * SS] = acc;
  }
}

// ---------------------------------------------------------------------------
// One WAVE per (b,m) row. Score row staged in LDS. Ballot binary-search
// threshold with cnt==16 early exit; compact; signed-abs-softmax; gather
// token rows; LN -> mv1. XCD b-affinity swizzle.
// ---------------------------------------------------------------------------
__global__ __launch_bounds__(256) void k_write(
    const float* __restrict__ scores, const float* __restrict__ token_val,
    const float* __restrict__ token_state, const float* __restrict__ mv0,
    const float* __restrict__ ms0, const float* __restrict__ ln_g,
    const float* __restrict__ ln_b, float* __restrict__ mv1,
    float* __restrict__ ms_w) {
  int t = threadIdx.x;
  int wave = t >> 6, lane = t & 63;
  int i = blockIdx.x;                 // 0..1023
  int slot = i >> 3;                  // 0..127
  int b = 2 * (i & 7) + (slot >> 6);  // two b per xcd
  int m = (slot & 63) * 4 + wave;
  int row = b * MM + m;
  __shared__ float srl[4][SS];        // 8KB per wave
  __shared__ int selj_sh[4][KK];
  float4* srl4 = reinterpret_cast<float4*>(&srl[wave][0]);
  const float* srow = scores + (size_t)row * SS;
  unsigned maxa = 0u;
#pragma unroll
  for (int ch = 0; ch < 8; ++ch) {
    float4 q = *reinterpret_cast<const float4*>(srow + (ch * 64 + lane) * 4);
    srl4[ch * 64 + lane] = q;
    maxa = max(maxa, __float_as_uint(q.x) & 0x7fffffffu);
    maxa = max(maxa, __float_as_uint(q.y) & 0x7fffffffu);
    maxa = max(maxa, __float_as_uint(q.z) & 0x7fffffffu);
    maxa = max(maxa, __float_as_uint(q.w) & 0x7fffffffu);
  }
#pragma unroll
  for (int off = 32; off > 0; off >>= 1)
    maxa = max(maxa, (unsigned)__shfl_xor((int)maxa, off));
  unsigned lo = 0u, hi = maxa, thr = 0u;
  bool early = false;
  while (lo < hi) {
    unsigned mid = lo + ((hi - lo + 1u) >> 1);
    int cnt = 0;
#pragma unroll
    for (int ch = 0; ch < 8; ++ch) {
      float4 q = srl4[ch * 64 + lane];
      cnt += __popcll(__ballot((__float_as_uint(q.x) & 0x7fffffffu) >= mid));
      cnt += __popcll(__ballot((__float_as_uint(q.y) & 0x7fffffffu) >= mid));
      cnt += __popcll(__ballot((__float_as_uint(q.z) & 0x7fffffffu) >= mid));
      cnt += __popcll(__ballot((__float_as_uint(q.w) & 0x7fffffffu) >= mid));
    }
    if (cnt == KK) { thr = mid; early = true; break; }
    if (cnt > KK) lo = mid; else hi = mid - 1u;
  }
  if (!early) thr = lo;
  unsigned long long ltmask = (1ull << lane) - 1ull;
  int s = 0;
  unsigned tiemask = 0u;
#pragma unroll
  for (int ch = 0; ch < 8; ++ch) {
    float4 q = srl4[ch * 64 + lane];
    unsigned a4[4] = {__float_as_uint(q.x) & 0x7fffffffu,
                      __float_as_uint(q.y) & 0x7fffffffu,
                      __float_as_uint(q.z) & 0x7fffffffu,
                      __float_as_uint(q.w) & 0x7fffffffu};
#pragma unroll
    for (int cc = 0; cc < 4; ++cc) {
      bool sg = early ? (a4[cc] >= thr) : (a4[cc] > thr);
      unsigned long long mk = __ballot(sg);
      if (sg) selj_sh[wave][s + __popcll(mk & ltmask)] = ch * 256 + lane * 4 + cc;
      s += __popcll(mk);
      if (!early && a4[cc] == thr) tiemask |= 1u << (ch * 4 + cc);
    }
  }
  int taken = s;
  while (taken < KK) {   // rare: fill ties by ascending index
    int myj = 0x7fffffff;
#pragma unroll
    for (int c = 0; c < 32; ++c)
      if ((tiemask >> c) & 1u) {
        int j = (c >> 2) * 256 + lane * 4 + (c & 3);
        myj = min(myj, j);
      }
    int wj = myj;
#pragma unroll
    for (int off = 32; off > 0; off >>= 1) wj = min(wj, __shfl_xor(wj, off));
    if (wj == 0x7fffffff) break;
    if (((wj >> 2) & 63) == lane) tiemask &= ~(1u << (((wj >> 8) << 2) | (wj & 3)));
    if (lane == 0) selj_sh[wave][taken] = wj;
    ++taken;
  }
  int js[KK];
  float es[KK];
#pragma unroll
  for (int k = 0; k < KK; ++k) {
    js[k] = selj_sh[wave][k];
    es[k] = srl[wave][js[k]];
  }
  float mx = 0.f;
#pragma unroll
  for (int k = 0; k < KK; ++k) mx = fmaxf(mx, fabsf(es[k]));
  float ssum = 0.f;
#pragma unroll
  for (int k = 0; k < KK; ++k) {
    float ex = expf(fabsf(es[k]) - mx);
    ssum += ex;
    es[k] = sgnf(es[k]) * ex;
  }
  float inv = 1.f / ssum;
  int dbase = lane * 8;
  const float* m0row = mv0 + m * DD + dbase;
  float4 a0 = *reinterpret_cast<const float4*>(m0row);
  float4 a1 = *reinterpret_cast<const float4*>(m0row + 4);
  float acc[8] = {a0.x, a0.y, a0.z, a0.w, a1.x, a1.y, a1.z, a1.w};
  float stacc = 0.f;
#pragma unroll
  for (int k = 0; k < KK; ++k) {
    float e = es[k] * inv;
    const float* tv = token_val + ((size_t)b * SS + js[k]) * DD + dbase;
    float4 u0 = *reinterpret_cast<const float4*>(tv);
    float4 u1 = *reinterpret_cast<const float4*>(tv + 4);
    acc[0] += e * u0.x; acc[1] += e * u0.y; acc[2] += e * u0.z; acc[3] += e * u0.w;
    acc[4] += e * u1.x; acc[5] += e * u1.y; acc[6] += e * u1.z; acc[7] += e * u1.w;
    stacc += e * token_state[(size_t)b * SS + js[k]];
  }
  if (lane == 0) ms_w[row] = ms0[m] + stacc;
  float s1 = 0.f, s2 = 0.f;
#pragma unroll
  for (int c = 0; c < 8; ++c) { s1 += acc[c]; s2 += acc[c] * acc[c]; }
  s1 = wave_sum(s1);
  s2 = wave_sum(s2);
  float mean = s1 * (1.0f / DD);
  float var = s2 * (1.0f / DD) - mean * mean;
  float rs = rsqrtf(var + 1e-5f);
  float4 g0 = *reinterpret_cast<const float4*>(ln_g + dbase);
  float4 g1 = *reinterpret_cast<const float4*>(ln_g + dbase + 4);
  float4 b0v = *reinterpret_cast<const float4*>(ln_b + dbase);
  float4 b1v = *reinterpret_cast<const float4*>(ln_b + dbase + 4);
  float4 o0, o1;
  o0.x = (acc[0] - mean) * rs * g0.x + b0v.x;
  o0.y = (acc[1] - mean) * rs * g0.y + b0v.y;
  o0.z = (acc[2] - mean) * rs * g0.z + b0v.z;
  o0.w = (acc[3] - mean) * rs * g0.w + b0v.w;
  o1.x = (acc[4] - mean) * rs * g1.x + b1v.x;
  o1.y = (acc[5] - mean) * rs * g1.y + b1v.y;
  o1.z = (acc[6] - mean) * rs * g1.z + b1v.z;
  o1.w = (acc[7] - mean) * rs * g1.w + b1v.w;
  float* orow = mv1 + (size_t)row * DD + dbase;
  *reinterpret_cast<float4*>(orow) = o0;
  *reinterpret_cast<float4*>(orow + 4) = o1;
}

// ---------------------------------------------------------------------------
// One WAVE per (b,m): pscores[j] = pt1[row,:]·ps1T[b,:,j] (ms1 folded in);
// ballot-threshold top-16 -> edges -> gather mv1 -> residual -> LN -> out.
// ---------------------------------------------------------------------------
__global__ __launch_bounds__(256, 4) void k_prop(
    const float* __restrict__ pt1, const float* __restrict__ ps1T,
    const float* __restrict__ mv1, const float* __restrict__ ln_g,
    const float* __restrict__ ln_b, float* __restrict__ out) {
  int t = threadIdx.x;
  int wave = t >> 6, lane = t & 63;
  int row = blockIdx.x * 4 + wave;          // row = b*MM + m
  int b = row >> 8, m = row & 255;
  __shared__ int selj_sh[4][KK];
  __shared__ float selv_sh[4][KK];
  float ptval = pt1[(size_t)row * RR + lane];
  const float* pB = ps1T + (size_t)b * RR * MM + lane * 4;
  float sc[4] = {0.f, 0.f, 0.f, 0.f};
#pragma unroll 8
  for (int r = 0; r < RR; ++r) {
    float w = __shfl(ptval, r);
    float4 pv = *reinterpret_cast<const float4*>(pB + r * MM);
    sc[0] += w * pv.x; sc[1] += w * pv.y; sc[2] += w * pv.z; sc[3] += w * pv.w;
  }
  int jbase = lane * 4;
  unsigned au[4];
#pragma unroll
  for (int c = 0; c < 4; ++c) au[c] = __float_as_uint(sc[c]) & 0x7fffffffu;
  unsigned lo = 0u, hi = 0x7f800000u, thr = 0u;
  bool early = false;
  while (lo < hi) {
    unsigned mid = lo + ((hi - lo + 1u) >> 1);
    int cnt = 0;
#pragma unroll
    for (int c = 0; c < 4; ++c) cnt += __popcll(__ballot(au[c] >= mid));
    if (cnt == KK) { thr = mid; early = true; break; }
    if (cnt > KK) lo = mid; else hi = mid - 1u;
  }
  if (!early) thr = lo;
  unsigned long long ltmask = (1ull << lane) - 1ull;
  int s = 0;
  unsigned tiemask = 0u;
#pragma unroll
  for (int c = 0; c < 4; ++c) {
    bool sg = early ? (au[c] >= thr) : (au[c] > thr);
    unsigned long long mk = __ballot(sg);
    if (sg) {
      int slot = s + __popcll(mk & ltmask);
      selj_sh[wave][slot] = jbase + c;
      selv_sh[wave][slot] = sc[c];
    }
    s += __popcll(mk);
    if (!early && au[c] == thr) tiemask |= 1u << c;
  }
  int taken = s;
  while (taken < KK) {
    int myj = 0x7fffffff;
#pragma unroll
    for (int c = 0; c < 4; ++c)
      if ((tiemask >> c) & 1u) myj = min(myj, jbase + c);
    int wj = myj;
#pragma unroll
    for (int off = 32; off > 0; off >>= 1) wj = min(wj, __shfl_xor(wj, off));
    if (wj == 0x7fffffff) break;
    if (wj >= jbase && wj < jbase + 4) {
      tiemask &= ~(1u << (wj - jbase));
      selv_sh[wave][taken] = sc[wj - jbase];
      if (lane == (wj >> 2)) selj_sh[wave][taken] = wj;
    }
    ++taken;
  }
  int js[KK];
  float es[KK];
#pragma unroll
  for (int k = 0; k < KK; ++k) { js[k] = selj_sh[wave][k]; es[k] = selv_sh[wave][k]; }
  float mx = 0.f;
#pragma unroll
  for (int k = 0; k < KK; ++k) mx = fmaxf(mx, fabsf(es[k]));
  float ssum = 0.f;
#pragma unroll
  for (int k = 0; k < KK; ++k) {
    float ex = expf(fabsf(es[k]) - mx);
    ssum += ex;
    es[k] = sgnf(es[k]) * ex;
  }
  float inv = 1.f / ssum;
  int dbase = lane * 8;
  const float* mrow = mv1 + (size_t)row * DD + dbase;
  float4 a0 = *reinterpret_cast<const float4*>(mrow);
  float4 a1 = *reinterpret_cast<const float4*>(mrow + 4);
  float acc[8] = {a0.x, a0.y, a0.z, a0.w, a1.x, a1.y, a1.z, a1.w};
#pragma unroll
  for (int k = 0; k < KK; ++k) {
    float e = es[k] * inv;
    const float* pv = mv1 + ((size_t)b * MM + js[k]) * DD + dbase;
    float4 u0 = *reinterpret_cast<const float4*>(pv);
    float4 u1 = *reinterpret_cast<const float4*>(pv + 4);
    acc[0] += e * u0.x; acc[1] += e * u0.y; acc[2] += e * u0.z; acc[3] += e * u0.w;
    acc[4] += e * u1.x; acc[5] += e * u1.y; acc[6] += e * u1.z; acc[7] += e * u1.w;
  }
  float s1 = 0.f, s2 = 0.f;
#pragma unroll
  for (int c = 0; c < 8; ++c) { s1 += acc[c]; s2 += acc[c] * acc[c]; }
  s1 = wave_sum(s1);
  s2 = wave_sum(s2);
  float mean = s1 * (1.0f / DD);
  float var = s2 * (1.0f / DD) - mean * mean;
  float rs = rsqrtf(var + 1e-5f);
  float4 g0 = *reinterpret_cast<const float4*>(ln_g + dbase);
  float4 g1 = *reinterpret_cast<const float4*>(ln_g + dbase + 4);
  float4 b0v = *reinterpret_cast<const float4*>(ln_b + dbase);
  float4 b1v = *reinterpret_cast<const float4*>(ln_b + dbase + 4);
  float4 o0, o1;
  o0.x = (acc[0] - mean) * rs * g0.x + b0v.x;
  o0.y = (acc[1] - mean) * rs * g0.y + b0v.y;
  o0.z = (acc[2] - mean) * rs * g0.z + b0v.z;
  o0.w = (acc[3] - mean) * rs * g0.w + b0v.w;
  o1.x = (acc[4] - mean) * rs * g1.x + b1v.x;
  o1.y = (acc[5] - mean) * rs * g1.y + b1v.y;
  o1.z = (acc[6] - mean) * rs * g1.z + b1v.z;
  o1.w = (acc[7] - mean) * rs * g1.w + b1v.w;
  float* orow = out + (size_t)row * DD + dbase;
  *reinterpret_cast<float4*>(orow) = o0;
  *reinterpret_cast<float4*>(orow + 4) = o1;
}

extern "C" void kernel_launch(void* const* d_in, const int* in_sizes, int n_in,
                              void* d_out, int out_size, void* d_ws,
                              size_t ws_size, hipStream_t stream) {
  const float* token_val = (const float*)d_in[0];
  const float* token_state = (const float*)d_in[1];
  const float* init_state = (const float*)d_in[2];
  const float* init_val = (const float*)d_in[3];
  const float* rUs_w = (const float*)d_in[4];
  const float* rUs_b = (const float*)d_in[5];
  const float* rUt_w = (const float*)d_in[6];
  const float* rUt_b = (const float*)d_in[7];
  const float* r_w = (const float*)d_in[8];
  const float* pUs_w = (const float*)d_in[9];
  const float* pUs_b = (const float*)d_in[10];
  const float* pUt_w = (const float*)d_in[11];
  const float* pUt_b = (const float*)d_in[12];
  const float* p_w = (const float*)d_in[13];
  const float* ln_g = (const float*)d_in[14];
  const float* ln_b = (const float*)d_in[15];
  float* out = (float*)d_out;

  float* ws = (float*)d_ws;
  float* mv0 = ws;    ws += MM * DD;
  float* pt0 = ws;    ws += MM * RR;
  float* ms0 = ws;    ws += MM;
  float* ps = ws;     ws += (size_t)BB * SS * RR;
  float* scores = ws; ws += (size_t)BB * MM * SS;
  float* mv1 = ws;    ws += (size_t)BB * MM * DD;
  float* ms_w = ws;   ws += BB * MM;
  float* ms1 = ws;    ws += BB * MM;
  float* pt1 = ws;    ws += (size_t)BB * MM * RR;
  float* ps1T = ws;   ws += (size_t)BB * RR * MM;

  k_init<<<MM, 256, 0, stream>>>(init_val, ln_g, ln_b, rUt_w, rUt_b, r_w, mv0, pt0);
  k_state_softmax<<<1, 256, 0, stream>>>(init_state, ms0);
  k_ps<<<(BB * SS) / 64, 256, 0, stream>>>(token_val, rUs_w, rUs_b, ps);
  dim3 gs(SS / 64, BB);
  k_scores<<<gs, 256, 0, stream>>>(pt0, ps, scores);
  k_write<<<(BB * MM) / 4, 256, 0, stream>>>(scores, token_val, token_state,
                                             mv0, ms0, ln_g, ln_b, mv1, ms_w);
  k_state_softmax<<<BB, 256, 0, stream>>>(ms_w, ms1);
  k_gemm_pair<<<256, 256, 0, stream>>>(mv1, pUt_w, pUt_b, p_w, pUs_w, pUs_b,
                                       ms1, pt1, ps1T);
  k_prop<<<(BB * MM) / 4, 256, 0, stream>>>(pt1, ps1T, mv1, ln_g, ln_b, out);
}

// Round 8
// 173.810 us; speedup vs baseline: 1.8630x; 1.8630x over previous
//
#include <hip/hip_runtime.h>
#include <hip/hip_bf16.h>
#include <math.h>

#define BB 16
#define SS 2048
#define DD 512
#define MM 256
#define RR 64
#define KK 16
#define GPAD 68  // LDS row pad: 272B stride = 16B-aligned, conflict-free reads

__device__ __forceinline__ float wave_sum(float v) {
#pragma unroll
  for (int off = 32; off > 0; off >>= 1) v += __shfl_xor(v, off);
  return v;
}

__device__ __forceinline__ float sgnf(float v) {
  return (v > 0.f) ? 1.f : ((v < 0.f) ? -1.f : 0.f);
}

// ---------------------------------------------------------------------------
// LN(init_val) -> mv0 [M,D]; pt0[m,r] = (mv0[m]·rUt_w[:,r] + rUt_b[r])*r_w[r]*0.1
// ---------------------------------------------------------------------------
__global__ __launch_bounds__(256) void k_init(
    const float* __restrict__ init_val, const float* __restrict__ ln_g,
    const float* __restrict__ ln_b, const float* __restrict__ rUt_w,
    const float* __restrict__ rUt_b, const float* __restrict__ r_w,
    float* __restrict__ mv0, float* __restrict__ pt0) {
  int m = blockIdx.x, t = threadIdx.x;
  __shared__ float row[DD];
  __shared__ float red[8];
  float x0 = init_val[m * DD + t];
  float x1 = init_val[m * DD + t + 256];
  float s = wave_sum(x0 + x1);
  float sq = wave_sum(x0 * x0 + x1 * x1);
  if ((t & 63) == 0) { red[t >> 6] = s; red[4 + (t >> 6)] = sq; }
  __syncthreads();
  float mean = (red[0] + red[1] + red[2] + red[3]) * (1.0f / DD);
  float var = (red[4] + red[5] + red[6] + red[7]) * (1.0f / DD) - mean * mean;
  float rs = rsqrtf(var + 1e-5f);
  float n0 = (x0 - mean) * rs * ln_g[t] + ln_b[t];
  float n1 = (x1 - mean) * rs * ln_g[t + 256] + ln_b[t + 256];
  mv0[m * DD + t] = n0;
  mv0[m * DD + t + 256] = n1;
  row[t] = n0;
  row[t + 256] = n1;
  __syncthreads();
  if (t < RR) {
    float acc = rUt_b[t];
    for (int d = 0; d < DD; ++d) acc += row[d] * rUt_w[d * RR + t];
    pt0[m * RR + t] = acc * r_w[t] * 0.1f;
  }
}

// ---------------------------------------------------------------------------
// signed_softmax_state over 256 elements per block-row
// ---------------------------------------------------------------------------
__global__ __launch_bounds__(256) void k_state_softmax(
    const float* __restrict__ in, float* __restrict__ out) {
  int b = blockIdx.x, t = threadIdx.x;
  __shared__ float red[4];
  float v = in[b * MM + t];
  float a = fabsf(v);
  float mx = a;
#pragma unroll
  for (int off = 32; off > 0; off >>= 1) mx = fmaxf(mx, __shfl_xor(mx, off));
  if ((t & 63) == 0) red[t >> 6] = mx;
  __syncthreads();
  mx = fmaxf(fmaxf(red[0], red[1]), fmaxf(red[2], red[3]));
  __syncthreads();
  float e = expf(a - mx);
  float ssum = wave_sum(e);
  if ((t & 63) == 0) red[t >> 6] = ssum;
  __syncthreads();
  ssum = red[0] + red[1] + red[2] + red[3];
  out[b * MM + t] = sgnf(v) * e / ssum * 4.0f;
}

// ---------------------------------------------------------------------------
// k_ps: ps[32768,64] = token_val[32768,512] @ rUs_w + bias.
// 128 rows x 64 cols per block (256 blocks), 256 threads, micro 8r x 4c:
// per k: 2 ds_read_b128 (A, transposed tile) + 1 ds_read_b128 (W) -> 32 FMA.
// K-chunk 32, next-chunk prefetched to regs (global latency hides under FMA).
// ---------------------------------------------------------------------------
__global__ __launch_bounds__(256) void k_ps(
    const float* __restrict__ A, const float* __restrict__ W,
    const float* __restrict__ bias, float* __restrict__ C) {
  __shared__ float Ast[32][128];  // [k][row] 16KB
  __shared__ float Ws[32][RR];    // [k][col] 8KB
  int t = threadIdx.x;
  int tx = t & 15;                // x4 cols
  int ty = t >> 4;                // x8 rows (per wave: ty 0..3 -> banks 0,8,16,24)
  int row0 = blockIdx.x * 128;
  float4 ra[4];
  float4 rw[2];
  // prologue: load chunk 0
#pragma unroll
  for (int i = 0; i < 4; ++i) {
    int slot = i * 256 + t;
    int r = slot >> 3, k4 = slot & 7;
    ra[i] = *reinterpret_cast<const float4*>(&A[(size_t)(row0 + r) * DD + k4 * 4]);
  }
#pragma unroll
  for (int i = 0; i < 2; ++i) {
    int slot = i * 256 + t;
    int k = slot >> 4, c4 = slot & 15;
    rw[i] = *reinterpret_cast<const float4*>(&W[(size_t)k * RR + c4 * 4]);
  }
  float acc[8][4] = {};
  for (int c = 0; c < 16; ++c) {
    __syncthreads();
#pragma unroll
    for (int i = 0; i < 4; ++i) {
      int slot = i * 256 + t;
      int r = slot >> 3, k4 = slot & 7;
      Ast[k4 * 4 + 0][r] = ra[i].x;
      Ast[k4 * 4 + 1][r] = ra[i].y;
      Ast[k4 * 4 + 2][r] = ra[i].z;
      Ast[k4 * 4 + 3][r] = ra[i].w;
    }
#pragma unroll
    for (int i = 0; i < 2; ++i) {
      int slot = i * 256 + t;
      int k = slot >> 4, c4 = slot & 15;
      *reinterpret_cast<float4*>(&Ws[k][c4 * 4]) = rw[i];
    }
    __syncthreads();
    if (c < 15) {
      int kc = (c + 1) * 32;
#pragma unroll
      for (int i = 0; i < 4; ++i) {
        int slot = i * 256 + t;
        int r = slot >> 3, k4 = slot & 7;
        ra[i] = *reinterpret_cast<const float4*>(
            &A[(size_t)(row0 + r) * DD + kc + k4 * 4]);
      }
#pragma unroll
      for (int i = 0; i < 2; ++i) {
        int slot = i * 256 + t;
        int k = slot >> 4, c4 = slot & 15;
        rw[i] = *reinterpret_cast<const float4*>(
            &W[(size_t)(kc + k) * RR + c4 * 4]);
      }
    }
#pragma unroll
    for (int k = 0; k < 32; ++k) {
      float4 alo = *reinterpret_cast<const float4*>(&Ast[k][ty * 8]);
      float4 ahi = *reinterpret_cast<const float4*>(&Ast[k][ty * 8 + 4]);
      float4 w4 = *reinterpret_cast<const float4*>(&Ws[k][tx * 4]);
      acc[0][0] += alo.x * w4.x; acc[0][1] += alo.x * w4.y; acc[0][2] += alo.x * w4.z; acc[0][3] += alo.x * w4.w;
      acc[1][0] += alo.y * w4.x; acc[1][1] += alo.y * w4.y; acc[1][2] += alo.y * w4.z; acc[1][3] += alo.y * w4.w;
      acc[2][0] += alo.z * w4.x; acc[2][1] += alo.z * w4.y; acc[2][2] += alo.z * w4.z; acc[2][3] += alo.z * w4.w;
      acc[3][0] += alo.w * w4.x; acc[3][1] += alo.w * w4.y; acc[3][2] += alo.w * w4.z; acc[3][3] += alo.w * w4.w;
      acc[4][0] += ahi.x * w4.x; acc[4][1] += ahi.x * w4.y; acc[4][2] += ahi.x * w4.z; acc[4][3] += ahi.x * w4.w;
      acc[5][0] += ahi.y * w4.x; acc[5][1] += ahi.y * w4.y; acc[5][2] += ahi.y * w4.z; acc[5][3] += ahi.y * w4.w;
      acc[6][0] += ahi.z * w4.x; acc[6][1] += ahi.z * w4.y; acc[6][2] += ahi.z * w4.z; acc[6][3] += ahi.z * w4.w;
      acc[7][0] += ahi.w * w4.x; acc[7][1] += ahi.w * w4.y; acc[7][2] += ahi.w * w4.z; acc[7][3] += ahi.w * w4.w;
    }
  }
  float4 bv = *reinterpret_cast<const float4*>(&bias[tx * 4]);
#pragma unroll
  for (int r = 0; r < 8; ++r) {
    int rr = row0 + ty * 8 + r;
    float4 o;
    o.x = acc[r][0] + bv.x; o.y = acc[r][1] + bv.y;
    o.z = acc[r][2] + bv.z; o.w = acc[r][3] + bv.w;
    *reinterpret_cast<float4*>(&C[(size_t)rr * RR + tx * 4]) = o;
  }
}

// ---------------------------------------------------------------------------
// gemm_body (R6, proven): 64-row tile, micro 4x4, K-chunk 32. Used for the
// small pair GEMM only.
// ---------------------------------------------------------------------------
template <bool TRANS_OUT>
__device__ __forceinline__ void gemm_body(
    const float* __restrict__ A, const float* __restrict__ W,
    const float* __restrict__ bias, const float* __restrict__ colscale,
    float csmul, const float* __restrict__ rowscale, float* __restrict__ C,
    int row0, float (*Ast)[GPAD], float (*Ws)[GPAD]) {
  int tid = threadIdx.x;
  int ty = tid >> 4, tx = tid & 15;
  float acc[4][4] = {};
  for (int kc = 0; kc < DD; kc += 32) {
#pragma unroll
    for (int i = 0; i < 2; ++i) {
      int s4 = i * 256 + tid;
      int r = s4 >> 3;
      int k4 = s4 & 7;
      float4 v = *reinterpret_cast<const float4*>(
          &A[(size_t)(row0 + r) * DD + kc + k4 * 4]);
      Ast[k4 * 4 + 0][r] = v.x;
      Ast[k4 * 4 + 1][r] = v.y;
      Ast[k4 * 4 + 2][r] = v.z;
      Ast[k4 * 4 + 3][r] = v.w;
    }
#pragma unroll
    for (int i = 0; i < 2; ++i) {
      int s4 = i * 256 + tid;
      int r = s4 >> 4;
      int c4 = s4 & 15;
      float4 v = *reinterpret_cast<const float4*>(
          &W[(size_t)(kc + r) * RR + c4 * 4]);
      *reinterpret_cast<float4*>(&Ws[r][c4 * 4]) = v;
    }
    __syncthreads();
#pragma unroll
    for (int k = 0; k < 32; ++k) {
      float4 a4 = *reinterpret_cast<const float4*>(&Ast[k][ty * 4]);
      float4 w4 = *reinterpret_cast<const float4*>(&Ws[k][tx * 4]);
      acc[0][0] += a4.x * w4.x; acc[0][1] += a4.x * w4.y;
      acc[0][2] += a4.x * w4.z; acc[0][3] += a4.x * w4.w;
      acc[1][0] += a4.y * w4.x; acc[1][1] += a4.y * w4.y;
      acc[1][2] += a4.y * w4.z; acc[1][3] += a4.y * w4.w;
      acc[2][0] += a4.z * w4.x; acc[2][1] += a4.z * w4.y;
      acc[2][2] += a4.z * w4.z; acc[2][3] += a4.z * w4.w;
      acc[3][0] += a4.w * w4.x; acc[3][1] += a4.w * w4.y;
      acc[3][2] += a4.w * w4.z; acc[3][3] += a4.w * w4.w;
    }
    __syncthreads();
  }
#pragma unroll
  for (int i = 0; i < 4; ++i) {
    int rr = row0 + ty * 4 + i;
    float rsc = rowscale ? rowscale[rr] : 1.f;
#pragma unroll
    for (int j = 0; j < 4; ++j) {
      int cc = tx * 4 + j;
      float v = acc[i][j] + bias[cc];
      if (colscale) v *= colscale[cc] * csmul;
      v *= rsc;
      if (TRANS_OUT) {
        C[((size_t)(rr >> 8) * RR + cc) * MM + (rr & 255)] = v;
      } else {
        C[(size_t)rr * RR + cc] = v;
      }
    }
  }
}

__global__ __launch_bounds__(256) void k_gemm_pair(
    const float* __restrict__ mv1, const float* __restrict__ pUt_w,
    const float* __restrict__ pUt_b, const float* __restrict__ p_w,
    const float* __restrict__ pUs_w, const float* __restrict__ pUs_b,
    const float* __restrict__ ms1, float* __restrict__ pt1,
    float* __restrict__ ps1T) {
  __shared__ float Ast[32][GPAD];
  __shared__ float Ws[32][GPAD];
  if (blockIdx.x < 64) {
    gemm_body<false>(mv1, pUt_w, pUt_b, p_w, 0.1f, nullptr, pt1,
                     blockIdx.x * 64, Ast, Ws);
  } else {
    gemm_body<true>(mv1, pUs_w, pUs_b, nullptr, 1.f, ms1, ps1T,
                    (blockIdx.x - 64) * 64, Ast, Ws);
  }
}

// ---------------------------------------------------------------------------
// k_scores: scores[b,m,j] = pt0[m,:]·ps[b,j,:] (K=64).
// Tile 64m x 128j, 256 threads, micro 4m x 8j. Both operands staged
// transposed ([k][m] / [k][j]) so reads are b128. PsT columns skewed +4 per
// 32 floats to kill the 4-way bank conflict.
// ---------------------------------------------------------------------------
#define PSW 144  // 128 + skew room
__device__ __forceinline__ int psw(int j) { return j + ((j >> 5) << 2); }

__global__ __launch_bounds__(256) void k_scores(
    const float* __restrict__ pt0, const float* __restrict__ ps,
    float* __restrict__ scores) {
  __shared__ float PtT[RR][64];   // [k][m] 16KB
  __shared__ float PsT[RR][PSW];  // [k][j skewed] 36KB
  int t = threadIdx.x;
  int b = blockIdx.z;
  int m0 = blockIdx.y * 64;
  int j0 = blockIdx.x * 128;
  {  // stage PtT: 4x4 reg transpose, 1 tile/thread
    int tm4 = t >> 4, tk4 = t & 15;
    const float* base = pt0 + (size_t)(m0 + tm4 * 4) * RR + tk4 * 4;
    float4 v0 = *reinterpret_cast<const float4*>(base);
    float4 v1 = *reinterpret_cast<const float4*>(base + RR);
    float4 v2 = *reinterpret_cast<const float4*>(base + 2 * RR);
    float4 v3 = *reinterpret_cast<const float4*>(base + 3 * RR);
    float4 w;
    w.x = v0.x; w.y = v1.x; w.z = v2.x; w.w = v3.x;
    *reinterpret_cast<float4*>(&PtT[tk4 * 4 + 0][tm4 * 4]) = w;
    w.x = v0.y; w.y = v1.y; w.z = v2.y; w.w = v3.y;
    *reinterpret_cast<float4*>(&PtT[tk4 * 4 + 1][tm4 * 4]) = w;
    w.x = v0.z; w.y = v1.z; w.z = v2.z; w.w = v3.z;
    *reinterpret_cast<float4*>(&PtT[tk4 * 4 + 2][tm4 * 4]) = w;
    w.x = v0.w; w.y = v1.w; w.z = v2.w; w.w = v3.w;
    *reinterpret_cast<float4*>(&PtT[tk4 * 4 + 3][tm4 * 4]) = w;
  }
#pragma unroll
  for (int ii = 0; ii < 2; ++ii) {  // stage PsT: 2 tiles/thread
    int slot = ii * 256 + t;
    int jt = slot >> 4, kt = slot & 15;
    const float* base = ps + ((size_t)b * SS + j0 + jt * 4) * RR + kt * 4;
    float4 v0 = *reinterpret_cast<const float4*>(base);
    float4 v1 = *reinterpret_cast<const float4*>(base + RR);
    float4 v2 = *reinterpret_cast<const float4*>(base + 2 * RR);
    float4 v3 = *reinterpret_cast<const float4*>(base + 3 * RR);
    int jc = psw(jt * 4);
    float4 w;
    w.x = v0.x; w.y = v1.x; w.z = v2.x; w.w = v3.x;
    *reinterpret_cast<float4*>(&PsT[kt * 4 + 0][jc]) = w;
    w.x = v0.y; w.y = v1.y; w.z = v2.y; w.w = v3.y;
    *reinterpret_cast<float4*>(&PsT[kt * 4 + 1][jc]) = w;
    w.x = v0.z; w.y = v1.z; w.z = v2.z; w.w = v3.z;
    *reinterpret_cast<float4*>(&PsT[kt * 4 + 2][jc]) = w;
    w.x = v0.w; w.y = v1.w; w.z = v2.w; w.w = v3.w;
    *reinterpret_cast<float4*>(&PsT[kt * 4 + 3][jc]) = w;
  }
  __syncthreads();
  int tj = t & 15;   // x8 j
  int tm = t >> 4;   // x4 m
  int jlo = psw(tj * 8);
  int jhi = psw(tj * 8 + 4);
  float acc[4][8] = {};
#pragma unroll
  for (int k = 0; k < RR; ++k) {
    float4 a4 = *reinterpret_cast<const float4*>(&PtT[k][tm * 4]);
    float4 w0 = *reinterpret_cast<const float4*>(&PsT[k][jlo]);
    float4 w1 = *reinterpret_cast<const float4*>(&PsT[k][jhi]);
    acc[0][0] += a4.x * w0.x; acc[0][1] += a4.x * w0.y; acc[0][2] += a4.x * w0.z; acc[0][3] += a4.x * w0.w;
    acc[0][4] += a4.x * w1.x; acc[0][5] += a4.x * w1.y; acc[0][6] += a4.x * w1.z; acc[0][7] += a4.x * w1.w;
    acc[1][0] += a4.y * w0.x; acc[1][1] += a4.y * w0.y; acc[1][2] += a4.y * w0.z; acc[1][3] += a4.y * w0.w;
    acc[1][4] += a4.y * w1.x; acc[1][5] += a4.y * w1.y; acc[1][6] += a4.y * w1.z; acc[1][7] += a4.y * w1.w;
    acc[2][0] += a4.z * w0.x; acc[2][1] += a4.z * w0.y; acc[2][2] += a4.z * w0.z; acc[2][3] += a4.z * w0.w;
    acc[2][4] += a4.z * w1.x; acc[2][5] += a4.z * w1.y; acc[2][6] += a4.z * w1.z; acc[2][7] += a4.z * w1.w;
    acc[3][0] += a4.w * w0.x; acc[3][1] += a4.w * w0.y; acc[3][2] += a4.w * w0.z; acc[3][3] += a4.w * w0.w;
    acc[3][4] += a4.w * w1.x; acc[3][5] += a4.w * w1.y; acc[3][6] += a4.w * w1.z; acc[3][7] += a4.w * w1.w;
  }
  float* obase = scores + (size_t)b * MM * SS + (size_t)(m0 + tm * 4) * SS + j0 + tj * 8;
#pragma unroll
  for (int i = 0; i < 4; ++i) {
    float4 o0, o1;
    o0.x = acc[i][0]; o0.y = acc[i][1]; o0.z = acc[i][2]; o0.w = acc[i][3];
    o1.x = acc[i][4]; o1.y = acc[i][5]; o1.z = acc[i][6]; o1.w = acc[i][7];
    *reinterpret_cast<float4*>(obase + (size_t)i * SS) = o0;
    *reinterpret_cast<float4*>(obase + (size_t)i * SS + 4) = o1;
  }
}

// ---------------------------------------------------------------------------
// One WAVE per (b,m) row. Score row staged in LDS. Ballot binary-search
// threshold with cnt==16 early exit; compact; signed-abs-softmax; gather
// token rows; LN -> mv1. XCD b-affinity swizzle. (R6, proven.)
// ---------------------------------------------------------------------------
__global__ __launch_bounds__(256) void k_write(
    const float* __restrict__ scores, const float* __restrict__ token_val,
    const float* __restrict__ token_state, const float* __restrict__ mv0,
    const float* __restrict__ ms0, const float* __restrict__ ln_g,
    const float* __restrict__ ln_b, float* __restrict__ mv1,
    float* __restrict__ ms_w) {
  int t = threadIdx.x;
  int wave = t >> 6, lane = t & 63;
  int i = blockIdx.x;                 // 0..1023
  int slot = i >> 3;                  // 0..127
  int b = 2 * (i & 7) + (slot >> 6);  // two b per xcd
  int m = (slot & 63) * 4 + wave;
  int row = b * MM + m;
  __shared__ float srl[4][SS];        // 8KB per wave
  __shared__ int selj_sh[4][KK];
  float4* srl4 = reinterpret_cast<float4*>(&srl[wave][0]);
  const float* srow = scores + (size_t)row * SS;
  unsigned maxa = 0u;
#pragma unroll
  for (int ch = 0; ch < 8; ++ch) {
    float4 q = *reinterpret_cast<const float4*>(srow + (ch * 64 + lane) * 4);
    srl4[ch * 64 + lane] = q;
    maxa = max(maxa, __float_as_uint(q.x) & 0x7fffffffu);
    maxa = max(maxa, __float_as_uint(q.y) & 0x7fffffffu);
    maxa = max(maxa, __float_as_uint(q.z) & 0x7fffffffu);
    maxa = max(maxa, __float_as_uint(q.w) & 0x7fffffffu);
  }
#pragma unroll
  for (int off = 32; off > 0; off >>= 1)
    maxa = max(maxa, (unsigned)__shfl_xor((int)maxa, off));
  unsigned lo = 0u, hi = maxa, thr = 0u;
  bool early = false;
  while (lo < hi) {
    unsigned mid = lo + ((hi - lo + 1u) >> 1);
    int cnt = 0;
#pragma unroll
    for (int ch = 0; ch < 8; ++ch) {
      float4 q = srl4[ch * 64 + lane];
      cnt += __popcll(__ballot((__float_as_uint(q.x) & 0x7fffffffu) >= mid));
      cnt += __popcll(__ballot((__float_as_uint(q.y) & 0x7fffffffu) >= mid));
      cnt += __popcll(__ballot((__float_as_uint(q.z) & 0x7fffffffu) >= mid));
      cnt += __popcll(__ballot((__float_as_uint(q.w) & 0x7fffffffu) >= mid));
    }
    if (cnt == KK) { thr = mid; early = true; break; }
    if (cnt > KK) lo = mid; else hi = mid - 1u;
  }
  if (!early) thr = lo;
  unsigned long long ltmask = (1ull << lane) - 1ull;
  int s = 0;
  unsigned tiemask = 0u;
#pragma unroll
  for (int ch = 0; ch < 8; ++ch) {
    float4 q = srl4[ch * 64 + lane];
    unsigned a4[4] = {__float_as_uint(q.x) & 0x7fffffffu,
                      __float_as_uint(q.y) & 0x7fffffffu,
                      __float_as_uint(q.z) & 0x7fffffffu,
                      __float_as_uint(q.w) & 0x7fffffffu};
#pragma unroll
    for (int cc = 0; cc < 4; ++cc) {
      bool sg = early ? (a4[cc] >= thr) : (a4[cc] > thr);
      unsigned long long mk = __ballot(sg);
      if (sg) selj_sh[wave][s + __popcll(mk & ltmask)] = ch * 256 + lane * 4 + cc;
      s += __popcll(mk);
      if (!early && a4[cc] == thr) tiemask |= 1u << (ch * 4 + cc);
    }
  }
  int taken = s;
  while (taken < KK) {   // rare: fill ties by ascending index
    int myj = 0x7fffffff;
#pragma unroll
    for (int c = 0; c < 32; ++c)
      if ((tiemask >> c) & 1u) {
        int j = (c >> 2) * 256 + lane * 4 + (c & 3);
        myj = min(myj, j);
      }
    int wj = myj;
#pragma unroll
    for (int off = 32; off > 0; off >>= 1) wj = min(wj, __shfl_xor(wj, off));
    if (wj == 0x7fffffff) break;
    if (((wj >> 2) & 63) == lane) tiemask &= ~(1u << (((wj >> 8) << 2) | (wj & 3)));
    if (lane == 0) selj_sh[wave][taken] = wj;
    ++taken;
  }
  int js[KK];
  float es[KK];
#pragma unroll
  for (int k = 0; k < KK; ++k) {
    js[k] = selj_sh[wave][k];
    es[k] = srl[wave][js[k]];
  }
  float mx = 0.f;
#pragma unroll
  for (int k = 0; k < KK; ++k) mx = fmaxf(mx, fabsf(es[k]));
  float ssum = 0.f;
#pragma unroll
  for (int k = 0; k < KK; ++k) {
    float ex = expf(fabsf(es[k]) - mx);
    ssum += ex;
    es[k] = sgnf(es[k]) * ex;
  }
  float inv = 1.f / ssum;
  int dbase = lane * 8;
  const float* m0row = mv0 + m * DD + dbase;
  float4 a0 = *reinterpret_cast<const float4*>(m0row);
  float4 a1 = *reinterpret_cast<const float4*>(m0row + 4);
  float acc[8] = {a0.x, a0.y, a0.z, a0.w, a1.x, a1.y, a1.z, a1.w};
  float stacc = 0.f;
#pragma unroll
  for (int k = 0; k < KK; ++k) {
    float e = es[k] * inv;
    const float* tv = token_val + ((size_t)b * SS + js[k]) * DD + dbase;
    float4 u0 = *reinterpret_cast<const float4*>(tv);
    float4 u1 = *reinterpret_cast<const float4*>(tv + 4);
    acc[0] += e * u0.x; acc[1] += e * u0.y; acc[2] += e * u0.z; acc[3] += e * u0.w;
    acc[4] += e * u1.x; acc[5] += e * u1.y; acc[6] += e * u1.z; acc[7] += e * u1.w;
    stacc += e * token_state[(size_t)b * SS + js[k]];
  }
  if (lane == 0) ms_w[row] = ms0[m] + stacc;
  float s1 = 0.f, s2 = 0.f;
#pragma unroll
  for (int c = 0; c < 8; ++c) { s1 += acc[c]; s2 += acc[c] * acc[c]; }
  s1 = wave_sum(s1);
  s2 = wave_sum(s2);
  float mean = s1 * (1.0f / DD);
  float var = s2 * (1.0f / DD) - mean * mean;
  float rs = rsqrtf(var + 1e-5f);
  float4 g0 = *reinterpret_cast<const float4*>(ln_g + dbase);
  float4 g1 = *reinterpret_cast<const float4*>(ln_g + dbase + 4);
  float4 b0v = *reinterpret_cast<const float4*>(ln_b + dbase);
  float4 b1v = *reinterpret_cast<const float4*>(ln_b + dbase + 4);
  float4 o0, o1;
  o0.x = (acc[0] - mean) * rs * g0.x + b0v.x;
  o0.y = (acc[1] - mean) * rs * g0.y + b0v.y;
  o0.z = (acc[2] - mean) * rs * g0.z + b0v.z;
  o0.w = (acc[3] - mean) * rs * g0.w + b0v.w;
  o1.x = (acc[4] - mean) * rs * g1.x + b1v.x;
  o1.y = (acc[5] - mean) * rs * g1.y + b1v.y;
  o1.z = (acc[6] - mean) * rs * g1.z + b1v.z;
  o1.w = (acc[7] - mean) * rs * g1.w + b1v.w;
  float* orow = mv1 + (size_t)row * DD + dbase;
  *reinterpret_cast<float4*>(orow) = o0;
  *reinterpret_cast<float4*>(orow + 4) = o1;
}

// ---------------------------------------------------------------------------
// One WAVE per (b,m): pscores[j] = pt1[row,:]·ps1T[b,:,j] (ms1 folded in);
// ballot-threshold top-16 -> edges -> gather mv1 -> residual -> LN -> out.
// (R6, proven.)
// ---------------------------------------------------------------------------
__global__ __launch_bounds__(256, 4) void k_prop(
    const float* __restrict__ pt1, const float* __restrict__ ps1T,
    const float* __restrict__ mv1, const float* __restrict__ ln_g,
    const float* __restrict__ ln_b, float* __restrict__ out) {
  int t = threadIdx.x;
  int wave = t >> 6, lane = t & 63;
  int row = blockIdx.x * 4 + wave;          // row = b*MM + m
  int b = row >> 8, m = row & 255;
  __shared__ int selj_sh[4][KK];
  __shared__ float selv_sh[4][KK];
  float ptval = pt1[(size_t)row * RR + lane];
  const float* pB = ps1T + (size_t)b * RR * MM + lane * 4;
  float sc[4] = {0.f, 0.f, 0.f, 0.f};
#pragma unroll 8
  for (int r = 0; r < RR; ++r) {
    float w = __shfl(ptval, r);
    float4 pv = *reinterpret_cast<const float4*>(pB + r * MM);
    sc[0] += w * pv.x; sc[1] += w * pv.y; sc[2] += w * pv.z; sc[3] += w * pv.w;
  }
  int jbase = lane * 4;
  unsigned au[4];
#pragma unroll
  for (int c = 0; c < 4; ++c) au[c] = __float_as_uint(sc[c]) & 0x7fffffffu;
  unsigned lo = 0u, hi = 0x7f800000u, thr = 0u;
  bool early = false;
  while (lo < hi) {
    unsigned mid = lo + ((hi - lo + 1u) >> 1);
    int cnt = 0;
#pragma unroll
    for (int c = 0; c < 4; ++c) cnt += __popcll(__ballot(au[c] >= mid));
    if (cnt == KK) { thr = mid; early = true; break; }
    if (cnt > KK) lo = mid; else hi = mid - 1u;
  }
  if (!early) thr = lo;
  unsigned long long ltmask = (1ull << lane) - 1ull;
  int s = 0;
  unsigned tiemask = 0u;
#pragma unroll
  for (int c = 0; c < 4; ++c) {
    bool sg = early ? (au[c] >= thr) : (au[c] > thr);
    unsigned long long mk = __ballot(sg);
    if (sg) {
      int slot = s + __popcll(mk & ltmask);
      selj_sh[wave][slot] = jbase + c;
      selv_sh[wave][slot] = sc[c];
    }
    s += __popcll(mk);
    if (!early && au[c] == thr) tiemask |= 1u << c;
  }
  int taken = s;
  while (taken < KK) {
    int myj = 0x7fffffff;
#pragma unroll
    for (int c = 0; c < 4; ++c)
      if ((tiemask >> c) & 1u) myj = min(myj, jbase + c);
    int wj = myj;
#pragma unroll
    for (int off = 32; off > 0; off >>= 1) wj = min(wj, __shfl_xor(wj, off));
    if (wj == 0x7fffffff) break;
    if (wj >= jbase && wj < jbase + 4) {
      tiemask &= ~(1u << (wj - jbase));
      selv_sh[wave][taken] = sc[wj - jbase];
      if (lane == (wj >> 2)) selj_sh[wave][taken] = wj;
    }
    ++taken;
  }
  int js[KK];
  float es[KK];
#pragma unroll
  for (int k = 0; k < KK; ++k) { js[k] = selj_sh[wave][k]; es[k] = selv_sh[wave][k]; }
  float mx = 0.f;
#pragma unroll
  for (int k = 0; k < KK; ++k) mx = fmaxf(mx, fabsf(es[k]));
  float ssum = 0.f;
#pragma unroll
  for (int k = 0; k < KK; ++k) {
    float ex = expf(fabsf(es[k]) - mx);
    ssum += ex;
    es[k] = sgnf(es[k]) * ex;
  }
  float inv = 1.f / ssum;
  int dbase = lane * 8;
  const float* mrow = mv1 + (size_t)row * DD + dbase;
  float4 a0 = *reinterpret_cast<const float4*>(mrow);
  float4 a1 = *reinterpret_cast<const float4*>(mrow + 4);
  float acc[8] = {a0.x, a0.y, a0.z, a0.w, a1.x, a1.y, a1.z, a1.w};
#pragma unroll
  for (int k = 0; k < KK; ++k) {
    float e = es[k] * inv;
    const float* pv = mv1 + ((size_t)b * MM + js[k]) * DD + dbase;
    float4 u0 = *reinterpret_cast<const float4*>(pv);
    float4 u1 = *reinterpret_cast<const float4*>(pv + 4);
    acc[0] += e * u0.x; acc[1] += e * u0.y; acc[2] += e * u0.z; acc[3] += e * u0.w;
    acc[4] += e * u1.x; acc[5] += e * u1.y; acc[6] += e * u1.z; acc[7] += e * u1.w;
  }
  float s1 = 0.f, s2 = 0.f;
#pragma unroll
  for (int c = 0; c < 8; ++c) { s1 += acc[c]; s2 += acc[c] * acc[c]; }
  s1 = wave_sum(s1);
  s2 = wave_sum(s2);
  float mean = s1 * (1.0f / DD);
  float var = s2 * (1.0f / DD) - mean * mean;
  float rs = rsqrtf(var + 1e-5f);
  float4 g0 = *reinterpret_cast<const float4*>(ln_g + dbase);
  float4 g1 = *reinterpret_cast<const float4*>(ln_g + dbase + 4);
  float4 b0v = *reinterpret_cast<const float4*>(ln_b + dbase);
  float4 b1v = *reinterpret_cast<const float4*>(ln_b + dbase + 4);
  float4 o0, o1;
  o0.x = (acc[0] - mean) * rs * g0.x + b0v.x;
  o0.y = (acc[1] - mean) * rs * g0.y + b0v.y;
  o0.z = (acc[2] - mean) * rs * g0.z + b0v.z;
  o0.w = (acc[3] - mean) * rs * g0.w + b0v.w;
  o1.x = (acc[4] - mean) * rs * g1.x + b1v.x;
  o1.y = (acc[5] - mean) * rs * g1.y + b1v.y;
  o1.z = (acc[6] - mean) * rs * g1.z + b1v.z;
  o1.w = (acc[7] - mean) * rs * g1.w + b1v.w;
  float* orow = out + (size_t)row * DD + dbase;
  *reinterpret_cast<float4*>(orow) = o0;
  *reinterpret_cast<float4*>(orow + 4) = o1;
}

extern "C" void kernel_launch(void* const* d_in, const int* in_sizes, int n_in,
                              void* d_out, int out_size, void* d_ws,
                              size_t ws_size, hipStream_t stream) {
  const float* token_val = (const float*)d_in[0];
  const float* token_state = (const float*)d_in[1];
  const float* init_state = (const float*)d_in[2];
  const float* init_val = (const float*)d_in[3];
  const float* rUs_w = (const float*)d_in[4];
  const float* rUs_b = (const float*)d_in[5];
  const float* rUt_w = (const float*)d_in[6];
  const float* rUt_b = (const float*)d_in[7];
  const float* r_w = (const float*)d_in[8];
  const float* pUs_w = (const float*)d_in[9];
  const float* pUs_b = (const float*)d_in[10];
  const float* pUt_w = (const float*)d_in[11];
  const float* pUt_b = (const float*)d_in[12];
  const float* p_w = (const float*)d_in[13];
  const float* ln_g = (const float*)d_in[14];
  const float* ln_b = (const float*)d_in[15];
  float* out = (float*)d_out;

  float* ws = (float*)d_ws;
  float* mv0 = ws;    ws += MM * DD;
  float* pt0 = ws;    ws += MM * RR;
  float* ms0 = ws;    ws += MM;
  float* ps = ws;     ws += (size_t)BB * SS * RR;
  float* scores = ws; ws += (size_t)BB * MM * SS;
  float* mv1 = ws;    ws += (size_t)BB * MM * DD;
  float* ms_w = ws;   ws += BB * MM;
  float* ms1 = ws;    ws += BB * MM;
  float* pt1 = ws;    ws += (size_t)BB * MM * RR;
  float* ps1T = ws;   ws += (size_t)BB * RR * MM;

  k_init<<<MM, 256, 0, stream>>>(init_val, ln_g, ln_b, rUt_w, rUt_b, r_w, mv0, pt0);
  k_state_softmax<<<1, 256, 0, stream>>>(init_state, ms0);
  k_ps<<<(BB * SS) / 128, 256, 0, stream>>>(token_val, rUs_w, rUs_b, ps);
  dim3 gs(SS / 128, MM / 64, BB);
  k_scores<<<gs, 256, 0, stream>>>(pt0, ps, scores);
  k_write<<<(BB * MM) / 4, 256, 0, stream>>>(scores, token_val, token_state,
                                             mv0, ms0, ln_g, ln_b, mv1, ms_w);
  k_state_softmax<<<BB, 256, 0, stream>>>(ms_w, ms1);
  k_gemm_pair<<<128, 256, 0, stream>>>(mv1, pUt_w, pUt_b, p_w, pUs_w, pUs_b,
                                       ms1, pt1, ps1T);
  k_prop<<<(BB * MM) / 4, 256, 0, stream>>>(pt1, ps1T, mv1, ln_g, ln_b, out);
}

// Round 9
// 164.238 us; speedup vs baseline: 1.9716x; 1.0583x over previous
//
#include <hip/hip_runtime.h>
#include <hip/hip_bf16.h>
#include <math.h>

#define BB 16
#define SS 2048
#define DD 512
#define MM 256
#define RR 64
#define KK 16
#define GPAD 68  // LDS row pad: 272B stride = 16B-aligned, conflict-free reads

__device__ __forceinline__ float wave_sum(float v) {
#pragma unroll
  for (int off = 32; off > 0; off >>= 1) v += __shfl_xor(v, off);
  return v;
}

__device__ __forceinline__ float sgnf(float v) {
  return (v > 0.f) ? 1.f : ((v < 0.f) ? -1.f : 0.f);
}

// ---------------------------------------------------------------------------
// LN(init_val) -> mv0 [M,D]; pt0[m,r] = (mv0[m]·rUt_w[:,r] + rUt_b[r])*r_w[r]*0.1
// ---------------------------------------------------------------------------
__global__ __launch_bounds__(256) void k_init(
    const float* __restrict__ init_val, const float* __restrict__ ln_g,
    const float* __restrict__ ln_b, const float* __restrict__ rUt_w,
    const float* __restrict__ rUt_b, const float* __restrict__ r_w,
    float* __restrict__ mv0, float* __restrict__ pt0) {
  int m = blockIdx.x, t = threadIdx.x;
  __shared__ float row[DD];
  __shared__ float red[8];
  float x0 = init_val[m * DD + t];
  float x1 = init_val[m * DD + t + 256];
  float s = wave_sum(x0 + x1);
  float sq = wave_sum(x0 * x0 + x1 * x1);
  if ((t & 63) == 0) { red[t >> 6] = s; red[4 + (t >> 6)] = sq; }
  __syncthreads();
  float mean = (red[0] + red[1] + red[2] + red[3]) * (1.0f / DD);
  float var = (red[4] + red[5] + red[6] + red[7]) * (1.0f / DD) - mean * mean;
  float rs = rsqrtf(var + 1e-5f);
  float n0 = (x0 - mean) * rs * ln_g[t] + ln_b[t];
  float n1 = (x1 - mean) * rs * ln_g[t + 256] + ln_b[t + 256];
  mv0[m * DD + t] = n0;
  mv0[m * DD + t + 256] = n1;
  row[t] = n0;
  row[t + 256] = n1;
  __syncthreads();
  if (t < RR) {
    float acc = rUt_b[t];
    for (int d = 0; d < DD; ++d) acc += row[d] * rUt_w[d * RR + t];
    pt0[m * RR + t] = acc * r_w[t] * 0.1f;
  }
}

// ---------------------------------------------------------------------------
// signed_softmax_state over 256 elements per block-row
// ---------------------------------------------------------------------------
__global__ __launch_bounds__(256) void k_state_softmax(
    const float* __restrict__ in, float* __restrict__ out) {
  int b = blockIdx.x, t = threadIdx.x;
  __shared__ float red[4];
  float v = in[b * MM + t];
  float a = fabsf(v);
  float mx = a;
#pragma unroll
  for (int off = 32; off > 0; off >>= 1) mx = fmaxf(mx, __shfl_xor(mx, off));
  if ((t & 63) == 0) red[t >> 6] = mx;
  __syncthreads();
  mx = fmaxf(fmaxf(red[0], red[1]), fmaxf(red[2], red[3]));
  __syncthreads();
  float e = expf(a - mx);
  float ssum = wave_sum(e);
  if ((t & 63) == 0) red[t >> 6] = ssum;
  __syncthreads();
  ssum = red[0] + red[1] + red[2] + red[3];
  out[b * MM + t] = sgnf(v) * e / ssum * 4.0f;
}

// ---------------------------------------------------------------------------
// k_ps split-K: 512 blocks; block bi: rows (bi&255)*128, K-half bi>>8.
// 256 threads, micro 8r x 4c: per k 3 ds_read_b128 -> 32 FMA.
// Conflict-free transposed staging: r = lane (+64), k4 = wave (+4) ->
// write bank = lane%32 = 2-way (free). Reg-prefetch of next chunk.
// half0 -> C0 (+bias), half1 -> C1 (no bias); consumer adds C0+C1.
// ---------------------------------------------------------------------------
__global__ __launch_bounds__(256) void k_ps(
    const float* __restrict__ A, const float* __restrict__ W,
    const float* __restrict__ bias, float* __restrict__ C0,
    float* __restrict__ C1) {
  __shared__ float Ast[32][128];  // [k][row] 16KB
  __shared__ float Ws[32][RR];    // [k][col] 8KB
  int t = threadIdx.x;
  int lane = t & 63;
  int wv = t >> 6;
  int tx = t & 15;                // x4 cols
  int ty = t >> 4;                // x8 rows
  int half = blockIdx.x >> 8;
  int row0 = (blockIdx.x & 255) * 128;
  int k0 = half * 256;
  float* C = half ? C1 : C0;
  float4 ra[4];
  float4 rw[2];
  // prologue: load chunk 0
#pragma unroll
  for (int i = 0; i < 4; ++i) {
    int r = (i & 1) * 64 + lane;
    int k4 = (i >> 1) * 4 + wv;
    ra[i] = *reinterpret_cast<const float4*>(
        &A[(size_t)(row0 + r) * DD + k0 + k4 * 4]);
  }
#pragma unroll
  for (int i = 0; i < 2; ++i) {
    int slot = i * 256 + t;
    int k = slot >> 4, c4 = slot & 15;
    rw[i] = *reinterpret_cast<const float4*>(&W[(size_t)(k0 + k) * RR + c4 * 4]);
  }
  float acc[8][4] = {};
  for (int c = 0; c < 8; ++c) {
    __syncthreads();
#pragma unroll
    for (int i = 0; i < 4; ++i) {
      int r = (i & 1) * 64 + lane;
      int k4 = (i >> 1) * 4 + wv;
      Ast[k4 * 4 + 0][r] = ra[i].x;
      Ast[k4 * 4 + 1][r] = ra[i].y;
      Ast[k4 * 4 + 2][r] = ra[i].z;
      Ast[k4 * 4 + 3][r] = ra[i].w;
    }
#pragma unroll
    for (int i = 0; i < 2; ++i) {
      int slot = i * 256 + t;
      int k = slot >> 4, c4 = slot & 15;
      *reinterpret_cast<float4*>(&Ws[k][c4 * 4]) = rw[i];
    }
    __syncthreads();
    if (c < 7) {
      int kc = k0 + (c + 1) * 32;
#pragma unroll
      for (int i = 0; i < 4; ++i) {
        int r = (i & 1) * 64 + lane;
        int k4 = (i >> 1) * 4 + wv;
        ra[i] = *reinterpret_cast<const float4*>(
            &A[(size_t)(row0 + r) * DD + kc + k4 * 4]);
      }
#pragma unroll
      for (int i = 0; i < 2; ++i) {
        int slot = i * 256 + t;
        int k = slot >> 4, c4 = slot & 15;
        rw[i] = *reinterpret_cast<const float4*>(
            &W[(size_t)(kc + k) * RR + c4 * 4]);
      }
    }
#pragma unroll
    for (int k = 0; k < 32; ++k) {
      float4 alo = *reinterpret_cast<const float4*>(&Ast[k][ty * 8]);
      float4 ahi = *reinterpret_cast<const float4*>(&Ast[k][ty * 8 + 4]);
      float4 w4 = *reinterpret_cast<const float4*>(&Ws[k][tx * 4]);
      acc[0][0] += alo.x * w4.x; acc[0][1] += alo.x * w4.y; acc[0][2] += alo.x * w4.z; acc[0][3] += alo.x * w4.w;
      acc[1][0] += alo.y * w4.x; acc[1][1] += alo.y * w4.y; acc[1][2] += alo.y * w4.z; acc[1][3] += alo.y * w4.w;
      acc[2][0] += alo.z * w4.x; acc[2][1] += alo.z * w4.y; acc[2][2] += alo.z * w4.z; acc[2][3] += alo.z * w4.w;
      acc[3][0] += alo.w * w4.x; acc[3][1] += alo.w * w4.y; acc[3][2] += alo.w * w4.z; acc[3][3] += alo.w * w4.w;
      acc[4][0] += ahi.x * w4.x; acc[4][1] += ahi.x * w4.y; acc[4][2] += ahi.x * w4.z; acc[4][3] += ahi.x * w4.w;
      acc[5][0] += ahi.y * w4.x; acc[5][1] += ahi.y * w4.y; acc[5][2] += ahi.y * w4.z; acc[5][3] += ahi.y * w4.w;
      acc[6][0] += ahi.z * w4.x; acc[6][1] += ahi.z * w4.y; acc[6][2] += ahi.z * w4.z; acc[6][3] += ahi.z * w4.w;
      acc[7][0] += ahi.w * w4.x; acc[7][1] += ahi.w * w4.y; acc[7][2] += ahi.w * w4.z; acc[7][3] += ahi.w * w4.w;
    }
  }
  float4 bv;
  if (half == 0) {
    bv = *reinterpret_cast<const float4*>(&bias[tx * 4]);
  } else {
    bv.x = bv.y = bv.z = bv.w = 0.f;
  }
#pragma unroll
  for (int r = 0; r < 8; ++r) {
    int rr = row0 + ty * 8 + r;
    float4 o;
    o.x = acc[r][0] + bv.x; o.y = acc[r][1] + bv.y;
    o.z = acc[r][2] + bv.z; o.w = acc[r][3] + bv.w;
    *reinterpret_cast<float4*>(&C[(size_t)rr * RR + tx * 4]) = o;
  }
}

// ---------------------------------------------------------------------------
// gemm_body (R6, proven): 64-row tile, micro 4x4, K-chunk 32. Small pair GEMM.
// ---------------------------------------------------------------------------
template <bool TRANS_OUT>
__device__ __forceinline__ void gemm_body(
    const float* __restrict__ A, const float* __restrict__ W,
    const float* __restrict__ bias, const float* __restrict__ colscale,
    float csmul, const float* __restrict__ rowscale, float* __restrict__ C,
    int row0, float (*Ast)[GPAD], float (*Ws)[GPAD]) {
  int tid = threadIdx.x;
  int ty = tid >> 4, tx = tid & 15;
  float acc[4][4] = {};
  for (int kc = 0; kc < DD; kc += 32) {
#pragma unroll
    for (int i = 0; i < 2; ++i) {
      int s4 = i * 256 + tid;
      int r = s4 >> 3;
      int k4 = s4 & 7;
      float4 v = *reinterpret_cast<const float4*>(
          &A[(size_t)(row0 + r) * DD + kc + k4 * 4]);
      Ast[k4 * 4 + 0][r] = v.x;
      Ast[k4 * 4 + 1][r] = v.y;
      Ast[k4 * 4 + 2][r] = v.z;
      Ast[k4 * 4 + 3][r] = v.w;
    }
#pragma unroll
    for (int i = 0; i < 2; ++i) {
      int s4 = i * 256 + tid;
      int r = s4 >> 4;
      int c4 = s4 & 15;
      float4 v = *reinterpret_cast<const float4*>(
          &W[(size_t)(kc + r) * RR + c4 * 4]);
      *reinterpret_cast<float4*>(&Ws[r][c4 * 4]) = v;
    }
    __syncthreads();
#pragma unroll
    for (int k = 0; k < 32; ++k) {
      float4 a4 = *reinterpret_cast<const float4*>(&Ast[k][ty * 4]);
      float4 w4 = *reinterpret_cast<const float4*>(&Ws[k][tx * 4]);
      acc[0][0] += a4.x * w4.x; acc[0][1] += a4.x * w4.y;
      acc[0][2] += a4.x * w4.z; acc[0][3] += a4.x * w4.w;
      acc[1][0] += a4.y * w4.x; acc[1][1] += a4.y * w4.y;
      acc[1][2] += a4.y * w4.z; acc[1][3] += a4.y * w4.w;
      acc[2][0] += a4.z * w4.x; acc[2][1] += a4.z * w4.y;
      acc[2][2] += a4.z * w4.z; acc[2][3] += a4.z * w4.w;
      acc[3][0] += a4.w * w4.x; acc[3][1] += a4.w * w4.y;
      acc[3][2] += a4.w * w4.z; acc[3][3] += a4.w * w4.w;
    }
    __syncthreads();
  }
#pragma unroll
  for (int i = 0; i < 4; ++i) {
    int rr = row0 + ty * 4 + i;
    float rsc = rowscale ? rowscale[rr] : 1.f;
#pragma unroll
    for (int j = 0; j < 4; ++j) {
      int cc = tx * 4 + j;
      float v = acc[i][j] + bias[cc];
      if (colscale) v *= colscale[cc] * csmul;
      v *= rsc;
      if (TRANS_OUT) {
        C[((size_t)(rr >> 8) * RR + cc) * MM + (rr & 255)] = v;
      } else {
        C[(size_t)rr * RR + cc] = v;
      }
    }
  }
}

__global__ __launch_bounds__(256) void k_gemm_pair(
    const float* __restrict__ mv1, const float* __restrict__ pUt_w,
    const float* __restrict__ pUt_b, const float* __restrict__ p_w,
    const float* __restrict__ pUs_w, const float* __restrict__ pUs_b,
    const float* __restrict__ ms1, float* __restrict__ pt1,
    float* __restrict__ ps1T) {
  __shared__ float Ast[32][GPAD];
  __shared__ float Ws[32][GPAD];
  if (blockIdx.x < 64) {
    gemm_body<false>(mv1, pUt_w, pUt_b, p_w, 0.1f, nullptr, pt1,
                     blockIdx.x * 64, Ast, Ws);
  } else {
    gemm_body<true>(mv1, pUs_w, pUs_b, nullptr, 1.f, ms1, ps1T,
                    (blockIdx.x - 64) * 64, Ast, Ws);
  }
}

// ---------------------------------------------------------------------------
// k_scores: scores[b,m,j] = pt0[m,:]·(ps0+ps1)[b,j,:] (K=64).
// Tile 64m x 128j, 256 threads, micro 4m x 8j; operands staged transposed.
// ---------------------------------------------------------------------------
#define PSW 144  // 128 + skew room
__device__ __forceinline__ int psw(int j) { return j + ((j >> 5) << 2); }

__global__ __launch_bounds__(256) void k_scores(
    const float* __restrict__ pt0, const float* __restrict__ ps0,
    const float* __restrict__ ps1, float* __restrict__ scores) {
  __shared__ float PtT[RR][64];   // [k][m] 16KB
  __shared__ float PsT[RR][PSW];  // [k][j skewed] 36KB
  int t = threadIdx.x;
  int b = blockIdx.z;
  int m0 = blockIdx.y * 64;
  int j0 = blockIdx.x * 128;
  {  // stage PtT: 4x4 reg transpose, 1 tile/thread
    int tm4 = t >> 4, tk4 = t & 15;
    const float* base = pt0 + (size_t)(m0 + tm4 * 4) * RR + tk4 * 4;
    float4 v0 = *reinterpret_cast<const float4*>(base);
    float4 v1 = *reinterpret_cast<const float4*>(base + RR);
    float4 v2 = *reinterpret_cast<const float4*>(base + 2 * RR);
    float4 v3 = *reinterpret_cast<const float4*>(base + 3 * RR);
    float4 w;
    w.x = v0.x; w.y = v1.x; w.z = v2.x; w.w = v3.x;
    *reinterpret_cast<float4*>(&PtT[tk4 * 4 + 0][tm4 * 4]) = w;
    w.x = v0.y; w.y = v1.y; w.z = v2.y; w.w = v3.y;
    *reinterpret_cast<float4*>(&PtT[tk4 * 4 + 1][tm4 * 4]) = w;
    w.x = v0.z; w.y = v1.z; w.z = v2.z; w.w = v3.z;
    *reinterpret_cast<float4*>(&PtT[tk4 * 4 + 2][tm4 * 4]) = w;
    w.x = v0.w; w.y = v1.w; w.z = v2.w; w.w = v3.w;
    *reinterpret_cast<float4*>(&PtT[tk4 * 4 + 3][tm4 * 4]) = w;
  }
#pragma unroll
  for (int ii = 0; ii < 2; ++ii) {  // stage PsT: 2 tiles/thread, sum halves
    int slot = ii * 256 + t;
    int jt = slot >> 4, kt = slot & 15;
    size_t off = ((size_t)b * SS + j0 + jt * 4) * RR + kt * 4;
    const float* base0 = ps0 + off;
    const float* base1 = ps1 + off;
    float4 v0 = *reinterpret_cast<const float4*>(base0);
    float4 v1 = *reinterpret_cast<const float4*>(base0 + RR);
    float4 v2 = *reinterpret_cast<const float4*>(base0 + 2 * RR);
    float4 v3 = *reinterpret_cast<const float4*>(base0 + 3 * RR);
    float4 u0 = *reinterpret_cast<const float4*>(base1);
    float4 u1 = *reinterpret_cast<const float4*>(base1 + RR);
    float4 u2 = *reinterpret_cast<const float4*>(base1 + 2 * RR);
    float4 u3 = *reinterpret_cast<const float4*>(base1 + 3 * RR);
    v0.x += u0.x; v0.y += u0.y; v0.z += u0.z; v0.w += u0.w;
    v1.x += u1.x; v1.y += u1.y; v1.z += u1.z; v1.w += u1.w;
    v2.x += u2.x; v2.y += u2.y; v2.z += u2.z; v2.w += u2.w;
    v3.x += u3.x; v3.y += u3.y; v3.z += u3.z; v3.w += u3.w;
    int jc = psw(jt * 4);
    float4 w;
    w.x = v0.x; w.y = v1.x; w.z = v2.x; w.w = v3.x;
    *reinterpret_cast<float4*>(&PsT[kt * 4 + 0][jc]) = w;
    w.x = v0.y; w.y = v1.y; w.z = v2.y; w.w = v3.y;
    *reinterpret_cast<float4*>(&PsT[kt * 4 + 1][jc]) = w;
    w.x = v0.z; w.y = v1.z; w.z = v2.z; w.w = v3.z;
    *reinterpret_cast<float4*>(&PsT[kt * 4 + 2][jc]) = w;
    w.x = v0.w; w.y = v1.w; w.z = v2.w; w.w = v3.w;
    *reinterpret_cast<float4*>(&PsT[kt * 4 + 3][jc]) = w;
  }
  __syncthreads();
  int tj = t & 15;   // x8 j
  int tm = t >> 4;   // x4 m
  int jlo = psw(tj * 8);
  int jhi = psw(tj * 8 + 4);
  float acc[4][8] = {};
#pragma unroll
  for (int k = 0; k < RR; ++k) {
    float4 a4 = *reinterpret_cast<const float4*>(&PtT[k][tm * 4]);
    float4 w0 = *reinterpret_cast<const float4*>(&PsT[k][jlo]);
    float4 w1 = *reinterpret_cast<const float4*>(&PsT[k][jhi]);
    acc[0][0] += a4.x * w0.x; acc[0][1] += a4.x * w0.y; acc[0][2] += a4.x * w0.z; acc[0][3] += a4.x * w0.w;
    acc[0][4] += a4.x * w1.x; acc[0][5] += a4.x * w1.y; acc[0][6] += a4.x * w1.z; acc[0][7] += a4.x * w1.w;
    acc[1][0] += a4.y * w0.x; acc[1][1] += a4.y * w0.y; acc[1][2] += a4.y * w0.z; acc[1][3] += a4.y * w0.w;
    acc[1][4] += a4.y * w1.x; acc[1][5] += a4.y * w1.y; acc[1][6] += a4.y * w1.z; acc[1][7] += a4.y * w1.w;
    acc[2][0] += a4.z * w0.x; acc[2][1] += a4.z * w0.y; acc[2][2] += a4.z * w0.z; acc[2][3] += a4.z * w0.w;
    acc[2][4] += a4.z * w1.x; acc[2][5] += a4.z * w1.y; acc[2][6] += a4.z * w1.z; acc[2][7] += a4.z * w1.w;
    acc[3][0] += a4.w * w0.x; acc[3][1] += a4.w * w0.y; acc[3][2] += a4.w * w0.z; acc[3][3] += a4.w * w0.w;
    acc[3][4] += a4.w * w1.x; acc[3][5] += a4.w * w1.y; acc[3][6] += a4.w * w1.z; acc[3][7] += a4.w * w1.w;
  }
  float* obase = scores + (size_t)b * MM * SS + (size_t)(m0 + tm * 4) * SS + j0 + tj * 8;
#pragma unroll
  for (int i = 0; i < 4; ++i) {
    float4 o0, o1;
    o0.x = acc[i][0]; o0.y = acc[i][1]; o0.z = acc[i][2]; o0.w = acc[i][3];
    o1.x = acc[i][4]; o1.y = acc[i][5]; o1.z = acc[i][6]; o1.w = acc[i][7];
    *reinterpret_cast<float4*>(obase + (size_t)i * SS) = o0;
    *reinterpret_cast<float4*>(obase + (size_t)i * SS + 4) = o1;
  }
}

// ---------------------------------------------------------------------------
// One WAVE per (b,m) row. Score row staged in LDS. Ballot binary-search
// threshold with cnt==16 early exit; compact; signed-abs-softmax; gather
// token rows; LN -> mv1. XCD b-affinity swizzle. (Proven.)
// ---------------------------------------------------------------------------
__global__ __launch_bounds__(256) void k_write(
    const float* __restrict__ scores, const float* __restrict__ token_val,
    const float* __restrict__ token_state, const float* __restrict__ mv0,
    const float* __restrict__ ms0, const float* __restrict__ ln_g,
    const float* __restrict__ ln_b, float* __restrict__ mv1,
    float* __restrict__ ms_w) {
  int t = threadIdx.x;
  int wave = t >> 6, lane = t & 63;
  int i = blockIdx.x;                 // 0..1023
  int slot = i >> 3;                  // 0..127
  int b = 2 * (i & 7) + (slot >> 6);  // two b per xcd
  int m = (slot & 63) * 4 + wave;
  int row = b * MM + m;
  __shared__ float srl[4][SS];        // 8KB per wave
  __shared__ int selj_sh[4][KK];
  float4* srl4 = reinterpret_cast<float4*>(&srl[wave][0]);
  const float* srow = scores + (size_t)row * SS;
  unsigned maxa = 0u;
#pragma unroll
  for (int ch = 0; ch < 8; ++ch) {
    float4 q = *reinterpret_cast<const float4*>(srow + (ch * 64 + lane) * 4);
    srl4[ch * 64 + lane] = q;
    maxa = max(maxa, __float_as_uint(q.x) & 0x7fffffffu);
    maxa = max(maxa, __float_as_uint(q.y) & 0x7fffffffu);
    maxa = max(maxa, __float_as_uint(q.z) & 0x7fffffffu);
    maxa = max(maxa, __float_as_uint(q.w) & 0x7fffffffu);
  }
#pragma unroll
  for (int off = 32; off > 0; off >>= 1)
    maxa = max(maxa, (unsigned)__shfl_xor((int)maxa, off));
  unsigned lo = 0u, hi = maxa, thr = 0u;
  bool early = false;
  while (lo < hi) {
    unsigned mid = lo + ((hi - lo + 1u) >> 1);
    int cnt = 0;
#pragma unroll
    for (int ch = 0; ch < 8; ++ch) {
      float4 q = srl4[ch * 64 + lane];
      cnt += __popcll(__ballot((__float_as_uint(q.x) & 0x7fffffffu) >= mid));
      cnt += __popcll(__ballot((__float_as_uint(q.y) & 0x7fffffffu) >= mid));
      cnt += __popcll(__ballot((__float_as_uint(q.z) & 0x7fffffffu) >= mid));
      cnt += __popcll(__ballot((__float_as_uint(q.w) & 0x7fffffffu) >= mid));
    }
    if (cnt == KK) { thr = mid; early = true; break; }
    if (cnt > KK) lo = mid; else hi = mid - 1u;
  }
  if (!early) thr = lo;
  unsigned long long ltmask = (1ull << lane) - 1ull;
  int s = 0;
  unsigned tiemask = 0u;
#pragma unroll
  for (int ch = 0; ch < 8; ++ch) {
    float4 q = srl4[ch * 64 + lane];
    unsigned a4[4] = {__float_as_uint(q.x) & 0x7fffffffu,
                      __float_as_uint(q.y) & 0x7fffffffu,
                      __float_as_uint(q.z) & 0x7fffffffu,
                      __float_as_uint(q.w) & 0x7fffffffu};
#pragma unroll
    for (int cc = 0; cc < 4; ++cc) {
      bool sg = early ? (a4[cc] >= thr) : (a4[cc] > thr);
      unsigned long long mk = __ballot(sg);
      if (sg) selj_sh[wave][s + __popcll(mk & ltmask)] = ch * 256 + lane * 4 + cc;
      s += __popcll(mk);
      if (!early && a4[cc] == thr) tiemask |= 1u << (ch * 4 + cc);
    }
  }
  int taken = s;
  while (taken < KK) {   // rare: fill ties by ascending index
    int myj = 0x7fffffff;
#pragma unroll
    for (int c = 0; c < 32; ++c)
      if ((tiemask >> c) & 1u) {
        int j = (c >> 2) * 256 + lane * 4 + (c & 3);
        myj = min(myj, j);
      }
    int wj = myj;
#pragma unroll
    for (int off = 32; off > 0; off >>= 1) wj = min(wj, __shfl_xor(wj, off));
    if (wj == 0x7fffffff) break;
    if (((wj >> 2) & 63) == lane) tiemask &= ~(1u << (((wj >> 8) << 2) | (wj & 3)));
    if (lane == 0) selj_sh[wave][taken] = wj;
    ++taken;
  }
  int js[KK];
  float es[KK];
#pragma unroll
  for (int k = 0; k < KK; ++k) {
    js[k] = selj_sh[wave][k];
    es[k] = srl[wave][js[k]];
  }
  float mx = 0.f;
#pragma unroll
  for (int k = 0; k < KK; ++k) mx = fmaxf(mx, fabsf(es[k]));
  float ssum = 0.f;
#pragma unroll
  for (int k = 0; k < KK; ++k) {
    float ex = expf(fabsf(es[k]) - mx);
    ssum += ex;
    es[k] = sgnf(es[k]) * ex;
  }
  float inv = 1.f / ssum;
  int dbase = lane * 8;
  const float* m0row = mv0 + m * DD + dbase;
  float4 a0 = *reinterpret_cast<const float4*>(m0row);
  float4 a1 = *reinterpret_cast<const float4*>(m0row + 4);
  float acc[8] = {a0.x, a0.y, a0.z, a0.w, a1.x, a1.y, a1.z, a1.w};
  float stacc = 0.f;
#pragma unroll
  for (int k = 0; k < KK; ++k) {
    float e = es[k] * inv;
    const float* tv = token_val + ((size_t)b * SS + js[k]) * DD + dbase;
    float4 u0 = *reinterpret_cast<const float4*>(tv);
    float4 u1 = *reinterpret_cast<const float4*>(tv + 4);
    acc[0] += e * u0.x; acc[1] += e * u0.y; acc[2] += e * u0.z; acc[3] += e * u0.w;
    acc[4] += e * u1.x; acc[5] += e * u1.y; acc[6] += e * u1.z; acc[7] += e * u1.w;
    stacc += e * token_state[(size_t)b * SS + js[k]];
  }
  if (lane == 0) ms_w[row] = ms0[m] + stacc;
  float s1 = 0.f, s2 = 0.f;
#pragma unroll
  for (int c = 0; c < 8; ++c) { s1 += acc[c]; s2 += acc[c] * acc[c]; }
  s1 = wave_sum(s1);
  s2 = wave_sum(s2);
  float mean = s1 * (1.0f / DD);
  float var = s2 * (1.0f / DD) - mean * mean;
  float rs = rsqrtf(var + 1e-5f);
  float4 g0 = *reinterpret_cast<const float4*>(ln_g + dbase);
  float4 g1 = *reinterpret_cast<const float4*>(ln_g + dbase + 4);
  float4 b0v = *reinterpret_cast<const float4*>(ln_b + dbase);
  float4 b1v = *reinterpret_cast<const float4*>(ln_b + dbase + 4);
  float4 o0, o1;
  o0.x = (acc[0] - mean) * rs * g0.x + b0v.x;
  o0.y = (acc[1] - mean) * rs * g0.y + b0v.y;
  o0.z = (acc[2] - mean) * rs * g0.z + b0v.z;
  o0.w = (acc[3] - mean) * rs * g0.w + b0v.w;
  o1.x = (acc[4] - mean) * rs * g1.x + b1v.x;
  o1.y = (acc[5] - mean) * rs * g1.y + b1v.y;
  o1.z = (acc[6] - mean) * rs * g1.z + b1v.z;
  o1.w = (acc[7] - mean) * rs * g1.w + b1v.w;
  float* orow = mv1 + (size_t)row * DD + dbase;
  *reinterpret_cast<float4*>(orow) = o0;
  *reinterpret_cast<float4*>(orow + 4) = o1;
}

// ---------------------------------------------------------------------------
// One WAVE per (b,m): pscores[j] = pt1[row,:]·ps1T[b,:,j] (ms1 folded in);
// ballot-threshold top-16 -> edges -> gather mv1 -> residual -> LN -> out.
// (Proven.)
// ---------------------------------------------------------------------------
__global__ __launch_bounds__(256, 4) void k_prop(
    const float* __restrict__ pt1, const float* __restrict__ ps1T,
    const float* __restrict__ mv1, const float* __restrict__ ln_g,
    const float* __restrict__ ln_b, float* __restrict__ out) {
  int t = threadIdx.x;
  int wave = t >> 6, lane = t & 63;
  int row = blockIdx.x * 4 + wave;          // row = b*MM + m
  int b = row >> 8, m = row & 255;
  __shared__ int selj_sh[4][KK];
  __shared__ float selv_sh[4][KK];
  float ptval = pt1[(size_t)row * RR + lane];
  const float* pB = ps1T + (size_t)b * RR * MM + lane * 4;
  float sc[4] = {0.f, 0.f, 0.f, 0.f};
#pragma unroll 8
  for (int r = 0; r < RR; ++r) {
    float w = __shfl(ptval, r);
    float4 pv = *reinterpret_cast<const float4*>(pB + r * MM);
    sc[0] += w * pv.x; sc[1] += w * pv.y; sc[2] += w * pv.z; sc[3] += w * pv.w;
  }
  int jbase = lane * 4;
  unsigned au[4];
#pragma unroll
  for (int c = 0; c < 4; ++c) au[c] = __float_as_uint(sc[c]) & 0x7fffffffu;
  unsigned lo = 0u, hi = 0x7f800000u, thr = 0u;
  bool early = false;
  while (lo < hi) {
    unsigned mid = lo + ((hi - lo + 1u) >> 1);
    int cnt = 0;
#pragma unroll
    for (int c = 0; c < 4; ++c) cnt += __popcll(__ballot(au[c] >= mid));
    if (cnt == KK) { thr = mid; early = true; break; }
    if (cnt > KK) lo = mid; else hi = mid - 1u;
  }
  if (!early) thr = lo;
  unsigned long long ltmask = (1ull << lane) - 1ull;
  int s = 0;
  unsigned tiemask = 0u;
#pragma unroll
  for (int c = 0; c < 4; ++c) {
    bool sg = early ? (au[c] >= thr) : (au[c] > thr);
    unsigned long long mk = __ballot(sg);
    if (sg) {
      int slot = s + __popcll(mk & ltmask);
      selj_sh[wave][slot] = jbase + c;
      selv_sh[wave][slot] = sc[c];
    }
    s += __popcll(mk);
    if (!early && au[c] == thr) tiemask |= 1u << c;
  }
  int taken = s;
  while (taken < KK) {
    int myj = 0x7fffffff;
#pragma unroll
    for (int c = 0; c < 4; ++c)
      if ((tiemask >> c) & 1u) myj = min(myj, jbase + c);
    int wj = myj;
#pragma unroll
    for (int off = 32; off > 0; off >>= 1) wj = min(wj, __shfl_xor(wj, off));
    if (wj == 0x7fffffff) break;
    if (wj >= jbase && wj < jbase + 4) {
      tiemask &= ~(1u << (wj - jbase));
      selv_sh[wave][taken] = sc[wj - jbase];
      if (lane == (wj >> 2)) selj_sh[wave][taken] = wj;
    }
    ++taken;
  }
  int js[KK];
  float es[KK];
#pragma unroll
  for (int k = 0; k < KK; ++k) { js[k] = selj_sh[wave][k]; es[k] = selv_sh[wave][k]; }
  float mx = 0.f;
#pragma unroll
  for (int k = 0; k < KK; ++k) mx = fmaxf(mx, fabsf(es[k]));
  float ssum = 0.f;
#pragma unroll
  for (int k = 0; k < KK; ++k) {
    float ex = expf(fabsf(es[k]) - mx);
    ssum += ex;
    es[k] = sgnf(es[k]) * ex;
  }
  float inv = 1.f / ssum;
  int dbase = lane * 8;
  const float* mrow = mv1 + (size_t)row * DD + dbase;
  float4 a0 = *reinterpret_cast<const float4*>(mrow);
  float4 a1 = *reinterpret_cast<const float4*>(mrow + 4);
  float acc[8] = {a0.x, a0.y, a0.z, a0.w, a1.x, a1.y, a1.z, a1.w};
#pragma unroll
  for (int k = 0; k < KK; ++k) {
    float e = es[k] * inv;
    const float* pv = mv1 + ((size_t)b * MM + js[k]) * DD + dbase;
    float4 u0 = *reinterpret_cast<const float4*>(pv);
    float4 u1 = *reinterpret_cast<const float4*>(pv + 4);
    acc[0] += e * u0.x; acc[1] += e * u0.y; acc[2] += e * u0.z; acc[3] += e * u0.w;
    acc[4] += e * u1.x; acc[5] += e * u1.y; acc[6] += e * u1.z; acc[7] += e * u1.w;
  }
  float s1 = 0.f, s2 = 0.f;
#pragma unroll
  for (int c = 0; c < 8; ++c) { s1 += acc[c]; s2 += acc[c] * acc[c]; }
  s1 = wave_sum(s1);
  s2 = wave_sum(s2);
  float mean = s1 * (1.0f / DD);
  float var = s2 * (1.0f / DD) - mean * mean;
  float rs = rsqrtf(var + 1e-5f);
  float4 g0 = *reinterpret_cast<const float4*>(ln_g + dbase);
  float4 g1 = *reinterpret_cast<const float4*>(ln_g + dbase + 4);
  float4 b0v = *reinterpret_cast<const float4*>(ln_b + dbase);
  float4 b1v = *reinterpret_cast<const float4*>(ln_b + dbase + 4);
  float4 o0, o1;
  o0.x = (acc[0] - mean) * rs * g0.x + b0v.x;
  o0.y = (acc[1] - mean) * rs * g0.y + b0v.y;
  o0.z = (acc[2] - mean) * rs * g0.z + b0v.z;
  o0.w = (acc[3] - mean) * rs * g0.w + b0v.w;
  o1.x = (acc[4] - mean) * rs * g1.x + b1v.x;
  o1.y = (acc[5] - mean) * rs * g1.y + b1v.y;
  o1.z = (acc[6] - mean) * rs * g1.z + b1v.z;
  o1.w = (acc[7] - mean) * rs * g1.w + b1v.w;
  float* orow = out + (size_t)row * DD + dbase;
  *reinterpret_cast<float4*>(orow) = o0;
  *reinterpret_cast<float4*>(orow + 4) = o1;
}

extern "C" void kernel_launch(void* const* d_in, const int* in_sizes, int n_in,
                              void* d_out, int out_size, void* d_ws,
                              size_t ws_size, hipStream_t stream) {
  const float* token_val = (const float*)d_in[0];
  const float* token_state = (const float*)d_in[1];
  const float* init_state = (const float*)d_in[2];
  const float* init_val = (const float*)d_in[3];
  const float* rUs_w = (const float*)d_in[4];
  const float* rUs_b = (const float*)d_in[5];
  const float* rUt_w = (const float*)d_in[6];
  const float* rUt_b = (const float*)d_in[7];
  const float* r_w = (const float*)d_in[8];
  const float* pUs_w = (const float*)d_in[9];
  const float* pUs_b = (const float*)d_in[10];
  const float* pUt_w = (const float*)d_in[11];
  const float* pUt_b = (const float*)d_in[12];
  const float* p_w = (const float*)d_in[13];
  const float* ln_g = (const float*)d_in[14];
  const float* ln_b = (const float*)d_in[15];
  float* out = (float*)d_out;

  float* ws = (float*)d_ws;
  float* mv0 = ws;    ws += MM * DD;
  float* pt0 = ws;    ws += MM * RR;
  float* ms0 = ws;    ws += MM;
  float* ps = ws;     ws += (size_t)BB * SS * RR;    // ps half-0
  float* scores = ws; ws += (size_t)BB * MM * SS;
  float* mv1 = ws;    ws += (size_t)BB * MM * DD;    // also aliases ps half-1
  float* ms_w = ws;   ws += BB * MM;
  float* ms1 = ws;    ws += BB * MM;
  float* pt1 = ws;    ws += (size_t)BB * MM * RR;
  float* ps1T = ws;   ws += (size_t)BB * RR * MM;
  float* psB = mv1;  // BB*SS*RR == BB*MM*DD (2097152 floats): safe alias;
                     // psB consumed by k_scores before k_write writes mv1.

  k_init<<<MM, 256, 0, stream>>>(init_val, ln_g, ln_b, rUt_w, rUt_b, r_w, mv0, pt0);
  k_state_softmax<<<1, 256, 0, stream>>>(init_state, ms0);
  k_ps<<<512, 256, 0, stream>>>(token_val, rUs_w, rUs_b, ps, psB);
  dim3 gs(SS / 128, MM / 64, BB);
  k_scores<<<gs, 256, 0, stream>>>(pt0, ps, psB, scores);
  k_write<<<(BB * MM) / 4, 256, 0, stream>>>(scores, token_val, token_state,
                                             mv0, ms0, ln_g, ln_b, mv1, ms_w);
  k_state_softmax<<<BB, 256, 0, stream>>>(ms_w, ms1);
  k_gemm_pair<<<128, 256, 0, stream>>>(mv1, pUt_w, pUt_b, p_w, pUs_w, pUs_b,
                                       ms1, pt1, ps1T);
  k_prop<<<(BB * MM) / 4, 256, 0, stream>>>(pt1, ps1T, mv1, ln_g, ln_b, out);
}